// Round 6
// baseline (1336.049 us; speedup 1.0000x reference)
//
#include <hip/hip_runtime.h>

// Problem constants
#define BATCH 256
#define SEQ   128
#define IDIM  1024     // 256 + 768
#define HDIM  1024
#define G3    3072     // 3*HDIM
#define RS    100      // padded row stride (dwords) of split-K LDS buffer

typedef __attribute__((ext_vector_type(8))) short bf16x8;
typedef __attribute__((ext_vector_type(4))) short s16x4;
typedef __attribute__((ext_vector_type(4))) float f32x4;

__device__ __forceinline__ short f2bf(float f) {
    union { float f; unsigned u; } x; x.f = f;
    unsigned r = x.u + 0x7fffu + ((x.u >> 16) & 1u);   // RNE
    return (short)(r >> 16);
}
__device__ __forceinline__ float bf2f(unsigned short u) {
    union { unsigned u; float f; } x; x.u = ((unsigned)u) << 16;
    return x.f;
}

// LLC-coherent ops: write-through / bypass L1+L2, coherent at Infinity Cache.
__device__ __forceinline__ void st_llc_b64(short* p, s16x4 v) {
    asm volatile("global_store_dwordx2 %0, %1, off sc0 sc1" :: "v"(p), "v"(v) : "memory");
}
__device__ __forceinline__ void st_llc_b32(unsigned* p, unsigned v) {
    asm volatile("global_store_dword %0, %1, off sc0 sc1" :: "v"(p), "v"(v) : "memory");
}
#define LDH(dst, p, OFF) \
    asm volatile("global_load_dwordx4 %0, %1, off offset:" OFF " sc0 sc1" \
                 : "=v"(dst) : "v"(p))
#define LDT(dst, p, OFF) \
    asm volatile("global_load_dwordx4 %0, %1, off offset:" OFF " sc0 sc1" \
                 : "=v"(dst) : "v"(p))
#define LDX(dst, p) \
    asm volatile("global_load_dwordx2 %0, %1, off" : "=v"(dst) : "v"(p))

// ---------------------------------------------------------------------------
// Kernel 1: convert W_ih and W_hh (f32, row-major (3072,1024)) to bf16.
__global__ void cvt_w(const float* __restrict__ wih, const float* __restrict__ whh,
                      short* __restrict__ wihb, short* __restrict__ whhb) {
    int i = blockIdx.x * 256 + threadIdx.x;
    const float* s; short* d; int j;
    if (i < 786432) { s = wih; d = wihb; j = i; }
    else            { s = whh; d = whhb; j = i - 786432; }
    const float4 v = *((const float4*)s + j);
    s16x4 o;
    o[0] = f2bf(v.x); o[1] = f2bf(v.y); o[2] = f2bf(v.z); o[3] = f2bf(v.w);
    *(s16x4*)(d + (size_t)j * 4) = o;
}

// ---------------------------------------------------------------------------
// Kernel 2: x_proj = concat(base,visual) @ W_ih^T + b_ih, stored bf16 at
// [(k*256 + b)*3072 + n].  128x128 tile, BK=64, 256 threads.
// 2-phase pipeline (R4: measured neutral vs serial — kept; it passed).
__global__ __launch_bounds__(256, 2) void gemm_xproj(
    const float* __restrict__ base, const float* __restrict__ vis,
    const short* __restrict__ wihb, const float* __restrict__ bih,
    short* __restrict__ xp)
{
    __shared__ union {
        struct { short A[2][128 * 64]; short B[2][128 * 64]; } ab;   // 64 KB dbuf
        short C[128 * 136];            // 136-short row stride (pad) for epilogue
    } sm;
    const int tid = threadIdx.x;
    const int bid = blockIdx.x;
    const int nt = bid % 24, mt = bid / 24;
    const int m0 = mt * 128, n0 = nt * 128;
    const int lane = tid & 63, w = tid >> 6;
    const int wm = w >> 1, wn = w & 1;
    const int l15 = lane & 15, quad = lane >> 4;

    f32x4 acc[4][4];
#pragma unroll
    for (int i = 0; i < 4; ++i)
#pragma unroll
        for (int j = 0; j < 4; ++j) acc[i][j] = (f32x4){0.f, 0.f, 0.f, 0.f};

    const int arow = tid >> 3;          // 0..31
    const int acol8 = (tid & 7) * 8;    // 0..56

    float4 pv0[4], pv1[4];              // A f32 prefetch regs (next K-tile)

    auto issueA = [&](int kt) {
        const int col = kt * 64 + acol8;    // block-uniform predicate (64 | 256)
#pragma unroll
        for (int is = 0; is < 4; ++is) {
            const int row = m0 + is * 32 + arow;
            const float* s = (col < 256)
                ? (base + (size_t)row * 256 + col)
                : (vis  + (size_t)row * 768 + (col - 256));
            pv0[is] = *(const float4*)s;
            pv1[is] = *(const float4*)(s + 4);
        }
    };
    auto stage = [&](int buf, int kt) {
        const int k0 = kt * 64;
#pragma unroll
        for (int is = 0; is < 4; ++is) {
            union { unsigned u[4]; bf16x8 v; } pk;
            asm("v_cvt_pk_bf16_f32 %0, %1, %2" : "=v"(pk.u[0]) : "v"(pv0[is].x), "v"(pv0[is].y));
            asm("v_cvt_pk_bf16_f32 %0, %1, %2" : "=v"(pk.u[1]) : "v"(pv0[is].z), "v"(pv0[is].w));
            asm("v_cvt_pk_bf16_f32 %0, %1, %2" : "=v"(pk.u[2]) : "v"(pv1[is].x), "v"(pv1[is].y));
            asm("v_cvt_pk_bf16_f32 %0, %1, %2" : "=v"(pk.u[3]) : "v"(pv1[is].z), "v"(pv1[is].w));
            *(bf16x8*)&sm.ab.A[buf][is * 2048 + tid * 8] = pk.v;
            __builtin_amdgcn_global_load_lds(
                (const __attribute__((address_space(1))) void*)(wihb + (size_t)(n0 + is * 32 + arow) * 1024 + k0 + acol8),
                (__attribute__((address_space(3))) void*)&sm.ab.B[buf][is * 2048 + tid * 8],
                16, 0, 0);
        }
    };

    issueA(0);
    stage(0, 0);
    issueA(1);
    __syncthreads();

    for (int kt = 0; kt < 16; ++kt) {
        const int cur = kt & 1, nxt = cur ^ 1;
        if (kt < 15) {
            stage(nxt, kt + 1);
            if (kt < 14) issueA(kt + 2);
        }
#pragma unroll
        for (int s2 = 0; s2 < 2; ++s2) {
            bf16x8 af[4], bfv[4];
#pragma unroll
            for (int i = 0; i < 4; ++i)
                af[i] = *(const bf16x8*)&sm.ab.A[cur][(wm * 64 + i * 16 + l15) * 64 + s2 * 32 + quad * 8];
#pragma unroll
            for (int j = 0; j < 4; ++j)
                bfv[j] = *(const bf16x8*)&sm.ab.B[cur][(wn * 64 + j * 16 + l15) * 64 + s2 * 32 + quad * 8];
#pragma unroll
            for (int i = 0; i < 4; ++i)
#pragma unroll
                for (int j = 0; j < 4; ++j)
                    acc[i][j] = __builtin_amdgcn_mfma_f32_16x16x32_bf16(af[i], bfv[j], acc[i][j], 0, 0, 0);
        }
        __syncthreads();
    }
#pragma unroll
    for (int j = 0; j < 4; ++j) {
        const int cn = wn * 64 + j * 16 + l15;
        const float bv = bih[n0 + cn];
#pragma unroll
        for (int i = 0; i < 4; ++i) {
            const int rb = wm * 64 + i * 16 + quad * 4;
#pragma unroll
            for (int r = 0; r < 4; ++r)
                sm.C[(rb + r) * 136 + cn] = f2bf(acc[i][j][r] + bv);
        }
    }
    __syncthreads();
    {
        const int row = tid >> 1, c0 = (tid & 1) * 64;
        const int gm = m0 + row;
        short* dst = xp + ((size_t)(gm & 127) * 256 + (size_t)(gm >> 7)) * 3072 + n0 + c0;
        const short* src = &sm.C[row * 136 + c0];
#pragma unroll
        for (int c = 0; c < 64; c += 8)
            *(bf16x8*)(dst + c) = *(const bf16x8*)(src + c);
    }
}

// ---------------------------------------------------------------------------
// Kernel 3: persistent GRU recurrence with SELF-VALIDATING h exchange.
// 256 blocks (1/CU) x 256 threads; block = (bt 0..7, ct 0..31).
// Change vs 716us R0 baseline: producer h-store drain + pre-flag barrier are
// DELETED from the critical path.  Each 8B h-granule (one thread's 4 bf16
// cols, a single atomic dwordx2) gets a 4B checksum tag
//   tag = (consume_step) ^ dlo ^ dhi
// in a parity-mirrored tag array (lives in the dead wihb region, zeroed
// between gemm and gru).  Producer: h store, tag store, flag store all
// fire-and-forget.  Consumer: R0-style flag poll is a pure HINT, then loads
// h + tags and validates; stale/partial granules fail checksum -> reload
// (rare; terminates once stores land, so no deadlock mode).  No ABA on the
// parity-shared tag buffers: validation is all-to-all within a group, so
// intra-group skew is capped at 1 step.
// SYNC-FENCE IDIOM (guide rule #18; R5's 27-operand tied waitcnt does not
// compile): plain `s_waitcnt vmcnt(0)` + `sched_barrier(0)` — the sched
// barrier stops register-only consumers (checksum VALU, MFMA, xn_ copies)
// from being scheduled above the wait.
__global__ __launch_bounds__(256, 1) void gru_rec(
    const short* __restrict__ xp, const short* __restrict__ whhb,
    const float* __restrict__ bhh, short* __restrict__ hbuf,   // 2 x 256*1024 bf16, zeroed
    float* __restrict__ out, unsigned* __restrict__ flags,     // 8*32 flags, zeroed
    unsigned* __restrict__ tags)                               // 2 x 65536 dwords, zeroed
{
    __shared__ float red[128 * RS];   // 51200 B split-K partials, padded stride
    const int tid = threadIdx.x;
    const int bid = blockIdx.x;
    const int bt = bid >> 5;       // batch group 0..7
    const int ct = bid & 31;       // col block  0..31
    const int lane = tid & 63, w = tid >> 6;
    const int l15 = lane & 15, quad = lane >> 4;
    const int bm0 = bt * 32;
    const int kbase = w * 256 + quad * 8;   // this wave's K-chunk

    // persistent W_hh fragments: 6 n-tiles x 8 k-iters
    bf16x8 Bf[6][8];
#pragma unroll
    for (int g = 0; g < 6; ++g) {
        const size_t col = (size_t)((g >> 1) * 1024 + ct * 32 + (g & 1) * 16 + l15);
#pragma unroll
        for (int kk = 0; kk < 8; ++kk)
            Bf[g][kk] = *(const bf16x8*)(whhb + col * 1024 + kbase + kk * 32);
    }

    // epilogue ownership: 1 row x 4 consecutive cols per thread
    const int er = tid >> 3;             // row within group, 0..31
    const int ec0 = (tid & 7) * 4;       // first col, 0..28
    const f32x4 bhr = *(const f32x4*)(bhh + ct * 32 + ec0);
    const f32x4 bhz = *(const f32x4*)(bhh + 1024 + ct * 32 + ec0);
    const f32x4 bhn = *(const f32x4*)(bhh + 2048 + ct * 32 + ec0);

    unsigned* const myflag = flags + bt * 32 + ct;
    const unsigned* const pollp = flags + bt * 32 + (lane & 31);

    // producer tag offset (consumer-major layout), from (row, col):
    // col = w*256 + quad*8 + kk*32 + j*4  <->  idx = w*64 + (quad*2+j)*8 + kk
    const int pcol = ct * 32 + ec0;
    const int tagoff = (bm0 + er) * 256 + (pcol >> 8) * 64
                     + ((((pcol >> 3) & 3) * 2 + ((pcol >> 2) & 1)) * 8)
                     + ((pcol >> 5) & 7);

    float hold[4] = {0.f, 0.f, 0.f, 0.f};
    s16x4 xc[3], xn_[3];
    xn_[0] = (s16x4){0,0,0,0}; xn_[1] = (s16x4){0,0,0,0}; xn_[2] = (s16x4){0,0,0,0};
    {
        const size_t rb = (size_t)(bm0 + er) * 3072 + ct * 32 + ec0;
#pragma unroll
        for (int g = 0; g < 3; ++g) xc[g] = *(const s16x4*)(xp + rb + g * 1024);
    }

    for (int step = 0; step < 128; ++step) {
        // --- flag poll: pure latency hint (data self-validates below) ---
        if (step > 0) {
            const unsigned tgt = (unsigned)step;
            unsigned fv;
            do {
                asm volatile("global_load_dword %0, %1, off sc0 sc1" : "=v"(fv) : "v"(pollp));
                asm volatile("s_waitcnt vmcnt(0)" : "+v"(fv) :: "memory");
            } while (__ballot(fv < tgt));
        }
        const short* hr_ = hbuf + (size_t)(step & 1) * (256 * 1024);
        short* hw_ = hbuf + (size_t)((step + 1) & 1) * (256 * 1024);
        const unsigned* tr_ = tags + (size_t)(step & 1) * 65536;
        unsigned* tw_ = tags + (size_t)((step + 1) & 1) * 65536;

        // --- h + tag loads with checksum validation (retry on stale) ---
        bf16x8 A0[8], A1[8];
        uint4 T0a, T0b, T0c, T0d, T1a, T1b, T1c, T1d;
        const short* p0 = hr_ + (size_t)(bm0 + l15) * 1024 + kbase;
        const short* p1 = p0 + 16 * 1024;
        const unsigned* tq0 = tr_ + (size_t)(bm0 + l15) * 256 + w * 64 + quad * 16;
        const unsigned* tq1 = tq0 + 16 * 256;
        const unsigned stepu = (unsigned)step;
        for (;;) {
            LDH(A0[0], p0, "0");   LDH(A0[1], p0, "64");  LDH(A0[2], p0, "128"); LDH(A0[3], p0, "192");
            LDH(A0[4], p0, "256"); LDH(A0[5], p0, "320"); LDH(A0[6], p0, "384"); LDH(A0[7], p0, "448");
            LDH(A1[0], p1, "0");   LDH(A1[1], p1, "64");  LDH(A1[2], p1, "128"); LDH(A1[3], p1, "192");
            LDH(A1[4], p1, "256"); LDH(A1[5], p1, "320"); LDH(A1[6], p1, "384"); LDH(A1[7], p1, "448");
            LDT(T0a, tq0, "0"); LDT(T0b, tq0, "16"); LDT(T0c, tq0, "32"); LDT(T0d, tq0, "48");
            LDT(T1a, tq1, "0"); LDT(T1b, tq1, "16"); LDT(T1c, tq1, "32"); LDT(T1d, tq1, "48");
            // guide rule #18 fence: wait, then full compile-time sched fence so
            // no register-only consumer is scheduled above the wait.
            asm volatile("s_waitcnt vmcnt(0)" ::: "memory");
            __builtin_amdgcn_sched_barrier(0);
            unsigned bad = 0;
#define CK(A, TJ0, TJ1, C) do { union { bf16x8 v; uint4 u; } _a; _a.v = (A); \
            bad |= ((TJ0).C ^ stepu ^ _a.u.x ^ _a.u.y); \
            bad |= ((TJ1).C ^ stepu ^ _a.u.z ^ _a.u.w); } while (0)
            CK(A0[0], T0a, T0c, x); CK(A0[1], T0a, T0c, y);
            CK(A0[2], T0a, T0c, z); CK(A0[3], T0a, T0c, w);
            CK(A0[4], T0b, T0d, x); CK(A0[5], T0b, T0d, y);
            CK(A0[6], T0b, T0d, z); CK(A0[7], T0b, T0d, w);
            CK(A1[0], T1a, T1c, x); CK(A1[1], T1a, T1c, y);
            CK(A1[2], T1a, T1c, z); CK(A1[3], T1a, T1c, w);
            CK(A1[4], T1b, T1d, x); CK(A1[5], T1b, T1d, y);
            CK(A1[6], T1b, T1d, z); CK(A1[7], T1b, T1d, w);
#undef CK
            if (__ballot(bad != 0) == 0) break;
        }
        // xp for this step: prefetched last step; the validation vmcnt(0) +
        // sched_barrier above guarantee xn_ has landed before this copy.
        if (step > 0) { xc[0] = xn_[0]; xc[1] = xn_[1]; xc[2] = xn_[2]; }
        // early xp prefetch for step+1 (lands during this step's compute;
        // next step's validation fence ties it before use).
        if (step < 127) {
            const short* rb = xp + ((size_t)(step + 1) * 256 + bm0 + er) * 3072 + ct * 32 + ec0;
            LDX(xn_[0], rb); LDX(xn_[1], rb + 1024); LDX(xn_[2], rb + 2048);
        }

        f32x4 acc[2][6];
#pragma unroll
        for (int i = 0; i < 2; ++i)
#pragma unroll
            for (int g = 0; g < 6; ++g) acc[i][g] = (f32x4){0.f, 0.f, 0.f, 0.f};
#pragma unroll
        for (int kk = 0; kk < 8; ++kk) {
#pragma unroll
            for (int g = 0; g < 6; ++g) {
                acc[0][g] = __builtin_amdgcn_mfma_f32_16x16x32_bf16(A0[kk], Bf[g][kk], acc[0][g], 0, 0, 0);
                acc[1][g] = __builtin_amdgcn_mfma_f32_16x16x32_bf16(A1[kk], Bf[g][kk], acc[1][g], 0, 0, 0);
            }
        }
        // split-K partials -> LDS (padded stride: 2-way max, conflict-free)
#pragma unroll
        for (int i = 0; i < 2; ++i)
#pragma unroll
            for (int g = 0; g < 6; ++g) {
                const int c96 = (g >> 1) * 32 + (g & 1) * 16 + l15;
                const int rb = w * 32 + i * 16 + quad * 4;
#pragma unroll
                for (int r = 0; r < 4; ++r)
                    red[(rb + r) * RS + c96] = acc[i][g][r];
            }
        __syncthreads();                 // barrier1: partials written -> read
        f32x4 sr = bhr, sz = bhz, sn = bhn;
#pragma unroll
        for (int ww = 0; ww < 4; ++ww) {
            const float* rbp = &red[(ww * 32 + er) * RS];
            sr += *(const f32x4*)(rbp + ec0);
            sz += *(const f32x4*)(rbp + 32 + ec0);
            sn += *(const f32x4*)(rbp + 64 + ec0);
        }
        __syncthreads();                 // barrier2: reads done -> red reusable
        // gates + state update + fire-and-forget publication (NO drain)
        s16x4 hpk;
#pragma unroll
        for (int i = 0; i < 4; ++i) {
            const float xr = bf2f((unsigned short)xc[0][i]);
            const float xz = bf2f((unsigned short)xc[1][i]);
            const float xnv = bf2f((unsigned short)xc[2][i]);
            const float rg = 1.f / (1.f + __expf(-(xr + sr[i])));
            const float zg = 1.f / (1.f + __expf(-(xz + sz[i])));
            const float e2 = __expf(2.f * (xnv + rg * sn[i]));
            const float ng = 1.f - 2.f / (e2 + 1.f);   // tanh, overflow-safe
            const float hv = (1.f - zg) * ng + zg * hold[i];
            hold[i] = hv;
            hpk[i] = f2bf(hv);
        }
        if (step < 127) {
            union { s16x4 v; unsigned u[2]; } hp; hp.v = hpk;
            st_llc_b64(&hw_[(size_t)(bm0 + er) * 1024 + ct * 32 + ec0], hpk);
            st_llc_b32(tw_ + tagoff, (unsigned)(step + 1) ^ hp.u[0] ^ hp.u[1]);
            if (tid == 0) st_llc_b32(myflag, (unsigned)(step + 1));
        }
    }
    float4 o4; o4.x = hold[0]; o4.y = hold[1]; o4.z = hold[2]; o4.w = hold[3];
    *(float4*)(out + (size_t)(bm0 + er) * 1024 + ct * 32 + ec0) = o4;
}

// ---------------------------------------------------------------------------
extern "C" void kernel_launch(void* const* d_in, const int* in_sizes, int n_in,
                              void* d_out, int out_size, void* d_ws, size_t ws_size,
                              hipStream_t stream) {
    (void)in_sizes; (void)n_in; (void)out_size; (void)ws_size;
    const float* base = (const float*)d_in[0];
    const float* vis  = (const float*)d_in[1];
    const float* wih  = (const float*)d_in[2];
    const float* whh  = (const float*)d_in[3];
    const float* bih  = (const float*)d_in[4];
    const float* bhh  = (const float*)d_in[5];

    char* ws = (char*)d_ws;
    short*    xp   = (short*)(ws + 0);                    // 201326592 B
    short*    wihb = (short*)(ws + 201326592);            //   6291456 B (dead after gemm -> tag arena)
    short*    whhb = (short*)(ws + 207618048);            //   6291456 B
    short*    hbuf = (short*)(ws + 213909504);            //   1048576 B (ping-pong)
    unsigned* flg  = (unsigned*)(ws + 214958080);         //      4096 B

    (void)hipMemsetAsync(hbuf, 0, 1048576, stream);       // h0 = 0 (both buffers)
    (void)hipMemsetAsync(flg, 0, 4096, stream);           // flags

    cvt_w<<<dim3(6144), dim3(256), 0, stream>>>(wih, whh, wihb, whhb);
    gemm_xproj<<<dim3(6144), dim3(256), 0, stream>>>(base, vis, wihb, bih, xp);
    // wihb is dead now; reuse its first 512 KB as the zeroed tag arena.
    (void)hipMemsetAsync(wihb, 0, 524288, stream);
    gru_rec<<<dim3(256), dim3(256), 0, stream>>>(xp, whhb, bhh, hbuf, (float*)d_out, flg,
                                                 (unsigned*)wihb);
}